// Round 2
// baseline (768.126 us; speedup 1.0000x reference)
//
#include <hip/hip_runtime.h>
#include <hip/hip_bf16.h>

typedef unsigned short ushort_t;
typedef _Float16 h2 __attribute__((ext_vector_type(2)));
typedef _Float16 half4_t __attribute__((ext_vector_type(4)));
typedef _Float16 half8_t __attribute__((ext_vector_type(8)));
typedef float f32x4 __attribute__((ext_vector_type(4)));
#define EPSQ 1e-8f

__device__ __forceinline__ float fdot2f(h2 a, h2 b, float c) {
#if __has_builtin(__builtin_amdgcn_fdot2)
  return __builtin_amdgcn_fdot2(a, b, c, false);
#else
  return fmaf((float)a.x, (float)b.x, fmaf((float)a.y, (float)b.y, c));
#endif
}
__device__ __forceinline__ h2 bc_h2(unsigned int v) { return __builtin_bit_cast(h2, v); }
__device__ __forceinline__ unsigned int bc_u32(h2 v) { return __builtin_bit_cast(unsigned int, v); }
__device__ __forceinline__ ushort_t bc_u16(_Float16 v) { return __builtin_bit_cast(ushort_t, v); }

// DPP row-rotate add: sums within 16-lane rows via VALU pipe (no LDS traffic).
template<int CTRL>
__device__ __forceinline__ float dpp_addf(float x) {
  int y = __builtin_amdgcn_update_dpp(0, __builtin_bit_cast(int, x), CTRL, 0xf, 0xf, false);
  return x + __builtin_bit_cast(float, y);
}

// ws layout (bytes):
//   wc16  [9][64][128] fp16 : off 0        size 147456   (conv1 weights, K-chunked)
//   pwB16 [64][160]    fp16 : off 147456   size 20480    (pconv weights, kk=k*48+ci)
//   Whs   [245760]     fp16 : off 167936   size 491520   (routing W, chunk-major: [(o*16+d)][c][8])
//   u16   [4096][384][8] fp16: off 659456  size 25165824
// total ~25.8 MB

// ---------------- K0: weight prep ----------------
__global__ __launch_bounds__(256) void k0_prep(
    const float* __restrict__ w1, const float* __restrict__ pw,
    const float* __restrict__ Wf,
    _Float16* __restrict__ wc16, _Float16* __restrict__ pwB16,
    _Float16* __restrict__ Whs)
{
  int i = blockIdx.x * 256 + threadIdx.x;   // grid 960*256 = 245760
  if (i < 73728) {
    int c  = i / 8192;
    int r  = i % 8192;
    int co = r >> 7;
    int k  = r & 127;
    wc16[i] = (co < 50) ? (_Float16)w1[co*1152 + k*9 + c] : (_Float16)0.f;
  }
  if (i < 10240) {
    int co2 = i / 160, kk = i % 160;
    int k = kk / 48, ci = kk % 48;
    float v = (k < 3 && ci < 42) ? pw[co2*126 + ci*3 + k] : 0.f;
    pwB16[i] = (_Float16)v;
  }
  // W permute to chunk-major: Wf idx i = ((o*384+c)*16+d)*8+i8
  // -> Whs[((o*16+d)*384+c)*8+i8]  (so k3's per-(o,d) load is lane-coalesced 16B/thread)
  {
    int i8 = i & 7;
    int r  = i >> 3;
    int d  = r & 15;
    int rc = r >> 4;
    int c  = rc % 384;
    int o  = rc / 384;
    Whs[(((o*16 + d)*384) + c)*8 + i8] = (_Float16)Wf[i];
  }
}

// ---------------- K12: MFMA conv1 + relu + MFMA pconv + squash (3 b per block) ----------------
__global__ __launch_bounds__(256) void k12_mfma(
    const float* __restrict__ x, const float* __restrict__ b1,
    const float* __restrict__ b2, const _Float16* __restrict__ wc16,
    const _Float16* __restrict__ pwB16, ushort_t* __restrict__ u16)
{
  __shared__ float smem[19728];
  _Float16* xh   = (_Float16*)smem;
  _Float16* hr16 = (_Float16*)smem;
  _Float16* pB   = (_Float16*)smem + 8736;
  float*    pbuf = smem + 9744;

  const int tid   = threadIdx.x;
  const int w     = tid >> 6;
  const int lane  = tid & 63;
  const int lc    = lane & 15;
  const int qd    = lane >> 4;
  const int gbase = blockIdx.x * 3;

  // ---- stage x: fp32 -> fp16 into padded rows ----
  for (int j = tid; j < 4800; j += 256) {
    int g = j / 1600, r = j - g*1600;
    int p = r >> 5, q = r & 31;
    int bb = gbase + g; if (bb > 4095) bb = 4095;
    float4 v = *(const float4*)(x + bb*6400 + p*128 + q*4);
    half4_t hv = {(_Float16)v.x, (_Float16)v.y, (_Float16)v.z, (_Float16)v.w};
    *(half4_t*)(xh + g*6800 + p*136 + q*4) = hv;
  }
  // ---- stage w chunk 0 into Bbuf0 ----
  {
    const uint4* wg = (const uint4*)wc16;
    uint4* dst = (uint4*)(xh + 20400);
#pragma unroll
    for (int it = 0; it < 4; ++it) {
      int f = it*256 + tid;
      dst[(f >> 4)*17 + (f & 15)] = wg[f];
    }
  }

  const _Float16* abase[2];
#pragma unroll
  for (int tm = 0; tm < 2; ++tm) {
    int m = 32*w + 16*tm + lc;
    if (m > 125) m = 125;
    int g = m / 42, l = m - g*42;
    abase[tm] = xh + g*6800 + l*136 + qd*8;
  }

  f32x4 acc[2][4];
#pragma unroll
  for (int tm = 0; tm < 2; ++tm)
#pragma unroll
    for (int tn = 0; tn < 4; ++tn)
      acc[tm][tn] = (f32x4){0.f, 0.f, 0.f, 0.f};

  __syncthreads();

  uint4 pf[4];
  for (int c = 0; c < 9; ++c) {
    if (c < 8) {
      const uint4* wg = (const uint4*)wc16 + (c + 1)*1024;
#pragma unroll
      for (int it = 0; it < 4; ++it) pf[it] = wg[it*256 + tid];
    }
    const _Float16* Bb = xh + 20400 + (c & 1)*8704;
    const _Float16* a0 = abase[0] + c*136;
    const _Float16* a1 = abase[1] + c*136;
#pragma unroll
    for (int kk = 0; kk < 128; kk += 32) {
      half8_t av0 = *(const half8_t*)(a0 + kk);
      half8_t av1 = *(const half8_t*)(a1 + kk);
#pragma unroll
      for (int tn = 0; tn < 4; ++tn) {
        half8_t bv = *(const half8_t*)(Bb + (16*tn + lc)*136 + qd*8 + kk);
        acc[0][tn] = __builtin_amdgcn_mfma_f32_16x16x32_f16(av0, bv, acc[0][tn], 0, 0, 0);
        acc[1][tn] = __builtin_amdgcn_mfma_f32_16x16x32_f16(av1, bv, acc[1][tn], 0, 0, 0);
      }
    }
    __syncthreads();
    if (c < 8) {
      uint4* dst = (uint4*)(xh + 20400 + ((c + 1) & 1)*8704);
#pragma unroll
      for (int it = 0; it < 4; ++it) {
        int f = it*256 + tid;
        dst[(f >> 4)*17 + (f & 15)] = pf[it];
      }
      __syncthreads();
    }
  }

  // ---- zero hr16 and stage pconv weights ----
  for (int j = tid; j < 4368; j += 256) smem[j] = 0.f;
  {
    const uint4* pg = (const uint4*)pwB16;
    uint4* dst = (uint4*)pB;
    for (int f = tid; f < 1280; f += 256) {
      int row = f / 20, cc = f - row*20;
      dst[row*21 + cc] = pg[f];
    }
  }
  __syncthreads();

  // ---- conv1 epilogue: bias+relu -> hr16[g][co][l] fp16 ----
#pragma unroll
  for (int tm = 0; tm < 2; ++tm) {
    int mb = 32*w + 16*tm + 4*qd;
#pragma unroll
    for (int tn = 0; tn < 4; ++tn) {
      int co = 16*tn + lc;
      if (co < 50) {
        float bias = b1[co];
#pragma unroll
        for (int r = 0; r < 4; ++r) {
          int m = mb + r;
          if (m < 126) {
            int g = m / 42, l = m - g*42;
            hr16[g*2912 + co*56 + l] = (_Float16)fmaxf(acc[tm][tn][r] + bias, 0.f);
          }
        }
      }
    }
  }
  __syncthreads();

  // ---- pconv MFMA: M=144, N=64, K=160 ----
  f32x4 acc2[3][4];
#pragma unroll
  for (int tm = 0; tm < 3; ++tm)
#pragma unroll
    for (int tn = 0; tn < 4; ++tn)
      acc2[tm][tn] = (f32x4){0.f, 0.f, 0.f, 0.f};

#pragma unroll
  for (int kc = 0; kc < 5; ++kc) {
    int kk0 = kc*32 + qd*8;
    int k   = (kk0 >= 144) ? 3 : (kk0 >= 96) ? 2 : (kk0 >= 48) ? 1 : 0;
    int ci0 = kk0 - k*48;
    half8_t bv[4];
#pragma unroll
    for (int tn = 0; tn < 4; ++tn)
      bv[tn] = *(const half8_t*)(pB + (16*tn + lc)*168 + kk0);
#pragma unroll
    for (int tm = 0; tm < 3; ++tm) {
      int T = w + 4*tm; int Tc = (T < 9) ? T : 8;
      int g = Tc/3, l2 = (Tc - g*3)*16 + lc;
      half8_t av = *(const half8_t*)(hr16 + g*2912 + (l2 + k)*56 + ci0);
#pragma unroll
      for (int tn = 0; tn < 4; ++tn)
        acc2[tm][tn] = __builtin_amdgcn_mfma_f32_16x16x32_f16(av, bv[tn], acc2[tm][tn], 0, 0, 0);
    }
  }

  // ---- pconv epilogue -> pbuf[g][co2][l2] ----
#pragma unroll
  for (int tm = 0; tm < 3; ++tm) {
    int T = w + 4*tm;
    if (T < 9) {
      int g = T/3, l2b = (T - g*3)*16;
#pragma unroll
      for (int tn = 0; tn < 4; ++tn) {
        int co2 = 16*tn + lc;
        float bias2 = b2[co2];
#pragma unroll
        for (int r = 0; r < 4; ++r) {
          int l2 = l2b + 4*qd + r;
          pbuf[g*3328 + co2*52 + l2] = acc2[tm][tn][r] + bias2;
        }
      }
    }
  }
  __syncthreads();

  // ---- squash all 3 g -> u16 (fp16) ----
  for (int idx = tid; idx < 1152; idx += 256) {
    int g = idx / 384, cap = idx - g*384;
    int bb = gbase + g;
    if (bb < 4096) {
      int co2 = cap / 6, gg = cap - co2*6;
      const float* pp = pbuf + g*3328 + co2*52 + gg*8;
      float4 a0 = *(const float4*)pp;
      float4 a1 = *(const float4*)(pp + 4);
      float sq = a0.x*a0.x + a0.y*a0.y + a0.z*a0.z + a0.w*a0.w
               + a1.x*a1.x + a1.y*a1.y + a1.z*a1.z + a1.w*a1.w;
      float sc = sq / ((1.f + sq) * (sqrtf(sq) + EPSQ));
      h2 p0 = {(_Float16)(a0.x*sc), (_Float16)(a0.y*sc)};
      h2 p1 = {(_Float16)(a0.z*sc), (_Float16)(a0.w*sc)};
      h2 p2 = {(_Float16)(a1.x*sc), (_Float16)(a1.y*sc)};
      h2 p3 = {(_Float16)(a1.z*sc), (_Float16)(a1.w*sc)};
      *(uint4*)(u16 + ((size_t)bb*384 + cap)*8) =
          make_uint4(bc_u32(p0), bc_u32(p1), bc_u32(p2), bc_u32(p3));
    }
  }
}

// ---------------- K3: u_hat + routing, register-resident. ----------------
// R9: LDS-resident u_hat (70-140KB) pins occupancy at 1 block/CU (R7/R8 evidence:
// OccupancyPercent ~17% in both, dur scales with block count). New design: thread t
// owns capsule c=t; u_hat lives ONLY in uhreg[40] (h2). s[o][d] reduction is a
// wave butterfly (4 DPP row_ror adds + shfl_xor 16/32) + 6-wave LDS combine
// (part[6][80] = 1.9KB). coef stays fp32 (better numerics than old fp16 coc16).
// LDS ~2.5KB -> occupancy VGPR-limited (~4+ waves/SIMD). W re-laid out chunk-major
// in k0 so W-phase loads are 1KB/instruction coalesced.
__global__ __launch_bounds__(384, 4) void k3_route(
    const ushort_t* __restrict__ u16, const _Float16* __restrict__ Whs,
    float* __restrict__ out)
{
  __shared__ __align__(16) float part[6][80];
  __shared__ __align__(16) ushort_t svh16[80];

  const int t    = threadIdx.x;
  const int b    = blockIdx.x;           // grid 4096, one batch per block
  const int w    = t >> 6;
  const int lane = t & 63;

  // load u (fp16); thread t owns capsule c = t
  uint4 uu0 = *(const uint4*)(u16 + ((size_t)b*384 + t)*8);
  h2 ua0[4] = {bc_h2(uu0.x), bc_h2(uu0.y), bc_h2(uu0.z), bc_h2(uu0.w)};

  // ---- W-phase: u_hat into registers only; chunk-major W, coalesced ----
  h2 uhreg[40];
  const uint4* wb = (const uint4*)Whs;
#pragma unroll
  for (int o = 0; o < 5; ++o) {
    const uint4* wp = wb + (size_t)(o*16)*384 + t;
#pragma unroll
    for (int dd = 0; dd < 8; ++dd) {
      uint4 w0 = wp[(size_t)(2*dd)*384];
      uint4 w1 = wp[(size_t)(2*dd + 1)*384];
      float s00 = fdot2f(bc_h2(w0.x), ua0[0], fdot2f(bc_h2(w0.y), ua0[1],
                  fdot2f(bc_h2(w0.z), ua0[2], fdot2f(bc_h2(w0.w), ua0[3], 0.f))));
      float s10 = fdot2f(bc_h2(w1.x), ua0[0], fdot2f(bc_h2(w1.y), ua0[1],
                  fdot2f(bc_h2(w1.z), ua0[2], fdot2f(bc_h2(w1.w), ua0[3], 0.f))));
      uhreg[o*8 + dd] = (h2){(_Float16)s00, (_Float16)s10};
    }
  }

  float lg[5] = {0.f, 0.f, 0.f, 0.f, 0.f};

  for (int it = 0; it < 3; ++it) {
    // softmax over o (thread-local, fp32 coef)
    float co[5];
    {
      float m = fmaxf(fmaxf(fmaxf(lg[0],lg[1]),fmaxf(lg[2],lg[3])),lg[4]);
      float Z = 0.f;
#pragma unroll
      for (int o = 0; o < 5; ++o) { co[o] = __expf(lg[o]-m); Z += co[o]; }
      float inv = 1.f / Z;
#pragma unroll
      for (int o = 0; o < 5; ++o) co[o] *= inv;
    }

    // s-phase: per-o 16-value wave reduction (DPP rows + shfl crossings),
    // then one designated lane per pair writes the wave partial.
#pragma unroll
    for (int o = 0; o < 5; ++o) {
      float pr[16];
#pragma unroll
      for (int dd = 0; dd < 8; ++dd) {
        h2 uh = uhreg[o*8 + dd];
        pr[2*dd]     = co[o] * (float)uh.x;
        pr[2*dd + 1] = co[o] * (float)uh.y;
      }
#pragma unroll
      for (int j = 0; j < 16; ++j) {
        float v = pr[j];
        v = dpp_addf<0x121>(v);   // row_ror:1
        v = dpp_addf<0x122>(v);   // row_ror:2
        v = dpp_addf<0x124>(v);   // row_ror:4
        v = dpp_addf<0x128>(v);   // row_ror:8  -> 16-lane row sums
        v += __shfl_xor(v, 16);
        v += __shfl_xor(v, 32);   // -> full 64-lane wave sum in all lanes
        pr[j] = v;
      }
#pragma unroll
      for (int j = 0; j < 8; ++j) {
        if (lane == o*8 + j) {
          *(float2*)&part[w][o*16 + 2*j] = make_float2(pr[2*j], pr[2*j + 1]);
        }
      }
    }
    __syncthreads();

    // stage-2: t<80 combines the 6 wave partials, squashes, broadcasts v
    if (t < 80) {
      float s = part[0][t] + part[1][t] + part[2][t]
              + part[3][t] + part[4][t] + part[5][t];
      float sq = s * s;
      sq += __shfl_xor(sq, 1);
      sq += __shfl_xor(sq, 2);
      sq += __shfl_xor(sq, 4);
      sq += __shfl_xor(sq, 8);   // sum over the 16 d of this o
      float f = sq / ((1.f + sq) * (sqrtf(sq) + EPSQ));
      if (it == 2) out[(size_t)b*80 + t] = s * f;
      else         svh16[t] = bc_u16((_Float16)(s * f));
    }
    __syncthreads();

    if (it < 2) {
      // logits update: dv = <tu, v> via packed fdot2 from registers + svh16
#pragma unroll
      for (int o = 0; o < 5; ++o) {
        uint4 s0 = *(const uint4*)&svh16[o*16];
        uint4 s1 = *(const uint4*)&svh16[o*16 + 8];
        float dv = 0.f;
        dv = fdot2f(uhreg[o*8+0], bc_h2(s0.x), dv);
        dv = fdot2f(uhreg[o*8+1], bc_h2(s0.y), dv);
        dv = fdot2f(uhreg[o*8+2], bc_h2(s0.z), dv);
        dv = fdot2f(uhreg[o*8+3], bc_h2(s0.w), dv);
        dv = fdot2f(uhreg[o*8+4], bc_h2(s1.x), dv);
        dv = fdot2f(uhreg[o*8+5], bc_h2(s1.y), dv);
        dv = fdot2f(uhreg[o*8+6], bc_h2(s1.z), dv);
        dv = fdot2f(uhreg[o*8+7], bc_h2(s1.w), dv);
        lg[o] += dv;
      }
    }
  }
}

extern "C" void kernel_launch(void* const* d_in, const int* in_sizes, int n_in,
                              void* d_out, int out_size, void* d_ws, size_t ws_size,
                              hipStream_t stream) {
  const float* x  = (const float*)d_in[0];
  const float* w1 = (const float*)d_in[1];
  const float* b1 = (const float*)d_in[2];
  const float* pw = (const float*)d_in[3];
  const float* b2 = (const float*)d_in[4];
  const float* Wf = (const float*)d_in[5];
  float* out = (float*)d_out;
  char* ws = (char*)d_ws;

  _Float16* wc16  = (_Float16*)(ws);
  _Float16* pwB16 = (_Float16*)(ws + 147456);
  _Float16* Whs   = (_Float16*)(ws + 167936);
  ushort_t* u16   = (ushort_t*)(ws + 659456);

  k0_prep<<<960, 256, 0, stream>>>(w1, pw, Wf, wc16, pwB16, Whs);
  k12_mfma<<<1366, 256, 0, stream>>>(x, b1, b2, wc16, pwB16, u16);
  k3_route<<<4096, 384, 0, stream>>>(u16, Whs, out);
}

// Round 3
// 455.129 us; speedup vs baseline: 1.6877x; 1.6877x over previous
//
#include <hip/hip_runtime.h>
#include <hip/hip_bf16.h>

typedef unsigned short ushort_t;
typedef _Float16 h2 __attribute__((ext_vector_type(2)));
typedef _Float16 half4_t __attribute__((ext_vector_type(4)));
typedef _Float16 half8_t __attribute__((ext_vector_type(8)));
typedef float f32x4 __attribute__((ext_vector_type(4)));
#define EPSQ 1e-8f

__device__ __forceinline__ float fdot2f(h2 a, h2 b, float c) {
#if __has_builtin(__builtin_amdgcn_fdot2)
  return __builtin_amdgcn_fdot2(a, b, c, false);
#else
  return fmaf((float)a.x, (float)b.x, fmaf((float)a.y, (float)b.y, c));
#endif
}
__device__ __forceinline__ h2 bc_h2(unsigned int v) { return __builtin_bit_cast(h2, v); }
__device__ __forceinline__ unsigned int bc_u32(h2 v) { return __builtin_bit_cast(unsigned int, v); }
__device__ __forceinline__ ushort_t bc_u16(_Float16 v) { return __builtin_bit_cast(ushort_t, v); }

// ws layout (bytes):
//   wc16  [9][64][128] fp16 : off 0        size 147456   (conv1 weights, K-chunked)
//   pwB16 [64][160]    fp16 : off 147456   size 20480    (pconv weights, kk=k*48+ci)
//   Whs   [245760]     fp16 : off 167936   size 491520   (routing W, chunk-major: [(o*16+d)][c][8])
//   u16   [4096][384][8] fp16: off 659456  size 25165824
// total ~25.8 MB

// ---------------- K0: weight prep ----------------
__global__ __launch_bounds__(256) void k0_prep(
    const float* __restrict__ w1, const float* __restrict__ pw,
    const float* __restrict__ Wf,
    _Float16* __restrict__ wc16, _Float16* __restrict__ pwB16,
    _Float16* __restrict__ Whs)
{
  int i = blockIdx.x * 256 + threadIdx.x;   // grid 960*256 = 245760
  if (i < 73728) {
    int c  = i / 8192;
    int r  = i % 8192;
    int co = r >> 7;
    int k  = r & 127;
    wc16[i] = (co < 50) ? (_Float16)w1[co*1152 + k*9 + c] : (_Float16)0.f;
  }
  if (i < 10240) {
    int co2 = i / 160, kk = i % 160;
    int k = kk / 48, ci = kk % 48;
    float v = (k < 3 && ci < 42) ? pw[co2*126 + ci*3 + k] : 0.f;
    pwB16[i] = (_Float16)v;
  }
  // W permute to chunk-major: Wf idx i = ((o*384+c)*16+d)*8+i8
  // -> Whs[((o*16+d)*384+c)*8+i8]  (so k3's per-(o,d) load is lane-coalesced 16B/thread)
  {
    int i8 = i & 7;
    int r  = i >> 3;
    int d  = r & 15;
    int rc = r >> 4;
    int c  = rc % 384;
    int o  = rc / 384;
    Whs[(((o*16 + d)*384) + c)*8 + i8] = (_Float16)Wf[i];
  }
}

// ---------------- K12: MFMA conv1 + relu + MFMA pconv + squash (3 b per block) ----------------
__global__ __launch_bounds__(256) void k12_mfma(
    const float* __restrict__ x, const float* __restrict__ b1,
    const float* __restrict__ b2, const _Float16* __restrict__ wc16,
    const _Float16* __restrict__ pwB16, ushort_t* __restrict__ u16)
{
  __shared__ float smem[19728];
  _Float16* xh   = (_Float16*)smem;
  _Float16* hr16 = (_Float16*)smem;
  _Float16* pB   = (_Float16*)smem + 8736;
  float*    pbuf = smem + 9744;

  const int tid   = threadIdx.x;
  const int w     = tid >> 6;
  const int lane  = tid & 63;
  const int lc    = lane & 15;
  const int qd    = lane >> 4;
  const int gbase = blockIdx.x * 3;

  // ---- stage x: fp32 -> fp16 into padded rows ----
  for (int j = tid; j < 4800; j += 256) {
    int g = j / 1600, r = j - g*1600;
    int p = r >> 5, q = r & 31;
    int bb = gbase + g; if (bb > 4095) bb = 4095;
    float4 v = *(const float4*)(x + bb*6400 + p*128 + q*4);
    half4_t hv = {(_Float16)v.x, (_Float16)v.y, (_Float16)v.z, (_Float16)v.w};
    *(half4_t*)(xh + g*6800 + p*136 + q*4) = hv;
  }
  // ---- stage w chunk 0 into Bbuf0 ----
  {
    const uint4* wg = (const uint4*)wc16;
    uint4* dst = (uint4*)(xh + 20400);
#pragma unroll
    for (int it = 0; it < 4; ++it) {
      int f = it*256 + tid;
      dst[(f >> 4)*17 + (f & 15)] = wg[f];
    }
  }

  const _Float16* abase[2];
#pragma unroll
  for (int tm = 0; tm < 2; ++tm) {
    int m = 32*w + 16*tm + lc;
    if (m > 125) m = 125;
    int g = m / 42, l = m - g*42;
    abase[tm] = xh + g*6800 + l*136 + qd*8;
  }

  f32x4 acc[2][4];
#pragma unroll
  for (int tm = 0; tm < 2; ++tm)
#pragma unroll
    for (int tn = 0; tn < 4; ++tn)
      acc[tm][tn] = (f32x4){0.f, 0.f, 0.f, 0.f};

  __syncthreads();

  uint4 pf[4];
  for (int c = 0; c < 9; ++c) {
    if (c < 8) {
      const uint4* wg = (const uint4*)wc16 + (c + 1)*1024;
#pragma unroll
      for (int it = 0; it < 4; ++it) pf[it] = wg[it*256 + tid];
    }
    const _Float16* Bb = xh + 20400 + (c & 1)*8704;
    const _Float16* a0 = abase[0] + c*136;
    const _Float16* a1 = abase[1] + c*136;
#pragma unroll
    for (int kk = 0; kk < 128; kk += 32) {
      half8_t av0 = *(const half8_t*)(a0 + kk);
      half8_t av1 = *(const half8_t*)(a1 + kk);
#pragma unroll
      for (int tn = 0; tn < 4; ++tn) {
        half8_t bv = *(const half8_t*)(Bb + (16*tn + lc)*136 + qd*8 + kk);
        acc[0][tn] = __builtin_amdgcn_mfma_f32_16x16x32_f16(av0, bv, acc[0][tn], 0, 0, 0);
        acc[1][tn] = __builtin_amdgcn_mfma_f32_16x16x32_f16(av1, bv, acc[1][tn], 0, 0, 0);
      }
    }
    __syncthreads();
    if (c < 8) {
      uint4* dst = (uint4*)(xh + 20400 + ((c + 1) & 1)*8704);
#pragma unroll
      for (int it = 0; it < 4; ++it) {
        int f = it*256 + tid;
        dst[(f >> 4)*17 + (f & 15)] = pf[it];
      }
      __syncthreads();
    }
  }

  // ---- zero hr16 and stage pconv weights ----
  for (int j = tid; j < 4368; j += 256) smem[j] = 0.f;
  {
    const uint4* pg = (const uint4*)pwB16;
    uint4* dst = (uint4*)pB;
    for (int f = tid; f < 1280; f += 256) {
      int row = f / 20, cc = f - row*20;
      dst[row*21 + cc] = pg[f];
    }
  }
  __syncthreads();

  // ---- conv1 epilogue: bias+relu -> hr16[g][co][l] fp16 ----
#pragma unroll
  for (int tm = 0; tm < 2; ++tm) {
    int mb = 32*w + 16*tm + 4*qd;
#pragma unroll
    for (int tn = 0; tn < 4; ++tn) {
      int co = 16*tn + lc;
      if (co < 50) {
        float bias = b1[co];
#pragma unroll
        for (int r = 0; r < 4; ++r) {
          int m = mb + r;
          if (m < 126) {
            int g = m / 42, l = m - g*42;
            hr16[g*2912 + co*56 + l] = (_Float16)fmaxf(acc[tm][tn][r] + bias, 0.f);
          }
        }
      }
    }
  }
  __syncthreads();

  // ---- pconv MFMA: M=144, N=64, K=160 ----
  f32x4 acc2[3][4];
#pragma unroll
  for (int tm = 0; tm < 3; ++tm)
#pragma unroll
    for (int tn = 0; tn < 4; ++tn)
      acc2[tm][tn] = (f32x4){0.f, 0.f, 0.f, 0.f};

#pragma unroll
  for (int kc = 0; kc < 5; ++kc) {
    int kk0 = kc*32 + qd*8;
    int k   = (kk0 >= 144) ? 3 : (kk0 >= 96) ? 2 : (kk0 >= 48) ? 1 : 0;
    int ci0 = kk0 - k*48;
    half8_t bv[4];
#pragma unroll
    for (int tn = 0; tn < 4; ++tn)
      bv[tn] = *(const half8_t*)(pB + (16*tn + lc)*168 + kk0);
#pragma unroll
    for (int tm = 0; tm < 3; ++tm) {
      int T = w + 4*tm; int Tc = (T < 9) ? T : 8;
      int g = Tc/3, l2 = (Tc - g*3)*16 + lc;
      half8_t av = *(const half8_t*)(hr16 + g*2912 + (l2 + k)*56 + ci0);
#pragma unroll
      for (int tn = 0; tn < 4; ++tn)
        acc2[tm][tn] = __builtin_amdgcn_mfma_f32_16x16x32_f16(av, bv[tn], acc2[tm][tn], 0, 0, 0);
    }
  }

  // ---- pconv epilogue -> pbuf[g][co2][l2] ----
#pragma unroll
  for (int tm = 0; tm < 3; ++tm) {
    int T = w + 4*tm;
    if (T < 9) {
      int g = T/3, l2b = (T - g*3)*16;
#pragma unroll
      for (int tn = 0; tn < 4; ++tn) {
        int co2 = 16*tn + lc;
        float bias2 = b2[co2];
#pragma unroll
        for (int r = 0; r < 4; ++r) {
          int l2 = l2b + 4*qd + r;
          pbuf[g*3328 + co2*52 + l2] = acc2[tm][tn][r] + bias2;
        }
      }
    }
  }
  __syncthreads();

  // ---- squash all 3 g -> u16 (fp16) ----
  for (int idx = tid; idx < 1152; idx += 256) {
    int g = idx / 384, cap = idx - g*384;
    int bb = gbase + g;
    if (bb < 4096) {
      int co2 = cap / 6, gg = cap - co2*6;
      const float* pp = pbuf + g*3328 + co2*52 + gg*8;
      float4 a0 = *(const float4*)pp;
      float4 a1 = *(const float4*)(pp + 4);
      float sq = a0.x*a0.x + a0.y*a0.y + a0.z*a0.z + a0.w*a0.w
               + a1.x*a1.x + a1.y*a1.y + a1.z*a1.z + a1.w*a1.w;
      float sc = sq / ((1.f + sq) * (sqrtf(sq) + EPSQ));
      h2 p0 = {(_Float16)(a0.x*sc), (_Float16)(a0.y*sc)};
      h2 p1 = {(_Float16)(a0.z*sc), (_Float16)(a0.w*sc)};
      h2 p2 = {(_Float16)(a1.x*sc), (_Float16)(a1.y*sc)};
      h2 p3 = {(_Float16)(a1.z*sc), (_Float16)(a1.w*sc)};
      *(uint4*)(u16 + ((size_t)bb*384 + cap)*8) =
          make_uint4(bc_u32(p0), bc_u32(p1), bc_u32(p2), bc_u32(p3));
    }
  }
}

// ---------------- K3: u_hat + routing, register-resident. ----------------
// R10: R9's __launch_bounds__(384,4) forced VGPR=64 -> uhreg[40] spilled to
// scratch -> 510 MB HBM traffic/dispatch (WRITE_SIZE 314MB) = the whole 546us.
// Fix: plain __launch_bounds__(384), let VGPRs float (~110, no spill).
// Also: s-phase reduce rewritten as multi-value halving butterfly (16 values
// over 64 lanes): per step each lane keeps/sends complementary value-halves
// (static reg indices, cndmask pairs), count 16->8->4->2->1 within the 16-lane
// row, then 2 cross-row shfls. ~85 instr/o vs ~190 for the per-j butterfly.
// Lane l<16 ends holding the full sum of j=bitrev4(l); jmap is address math.
__global__ __launch_bounds__(384) void k3_route(
    const ushort_t* __restrict__ u16, const _Float16* __restrict__ Whs,
    float* __restrict__ out)
{
  __shared__ __align__(16) float part[6][80];
  __shared__ __align__(16) ushort_t svh16[80];

  const int t    = threadIdx.x;
  const int b    = blockIdx.x;           // grid 4096, one batch per block
  const int w    = t >> 6;
  const int lane = t & 63;
  // bitrev4 of lane&15: which j this lane holds after the halving butterfly
  const int jmap = ((lane & 1) << 3) | ((lane & 2) << 1) | ((lane & 4) >> 1) | ((lane & 8) >> 3);

  // load u (fp16); thread t owns capsule c = t
  uint4 uu0 = *(const uint4*)(u16 + ((size_t)b*384 + t)*8);
  h2 ua0[4] = {bc_h2(uu0.x), bc_h2(uu0.y), bc_h2(uu0.z), bc_h2(uu0.w)};

  // ---- W-phase: u_hat into registers only; chunk-major W, coalesced ----
  h2 uhreg[40];
  const uint4* wb = (const uint4*)Whs;
#pragma unroll
  for (int o = 0; o < 5; ++o) {
    const uint4* wp = wb + (size_t)(o*16)*384 + t;
#pragma unroll
    for (int dd = 0; dd < 8; ++dd) {
      uint4 w0 = wp[(size_t)(2*dd)*384];
      uint4 w1 = wp[(size_t)(2*dd + 1)*384];
      float s00 = fdot2f(bc_h2(w0.x), ua0[0], fdot2f(bc_h2(w0.y), ua0[1],
                  fdot2f(bc_h2(w0.z), ua0[2], fdot2f(bc_h2(w0.w), ua0[3], 0.f))));
      float s10 = fdot2f(bc_h2(w1.x), ua0[0], fdot2f(bc_h2(w1.y), ua0[1],
                  fdot2f(bc_h2(w1.z), ua0[2], fdot2f(bc_h2(w1.w), ua0[3], 0.f))));
      uhreg[o*8 + dd] = (h2){(_Float16)s00, (_Float16)s10};
    }
  }

  float lg[5] = {0.f, 0.f, 0.f, 0.f, 0.f};

  const bool s0 = (lane & 1) != 0;
  const bool s1 = (lane & 2) != 0;
  const bool s2 = (lane & 4) != 0;
  const bool s3 = (lane & 8) != 0;

  for (int it = 0; it < 3; ++it) {
    // softmax over o (thread-local, fp32 coef)
    float co[5];
    {
      float m = fmaxf(fmaxf(fmaxf(lg[0],lg[1]),fmaxf(lg[2],lg[3])),lg[4]);
      float Z = 0.f;
#pragma unroll
      for (int o = 0; o < 5; ++o) { co[o] = __expf(lg[o]-m); Z += co[o]; }
      float inv = 1.f / Z;
#pragma unroll
      for (int o = 0; o < 5; ++o) co[o] *= inv;
    }

    // s-phase: multi-value halving butterfly per o.
#pragma unroll
    for (int o = 0; o < 5; ++o) {
      float v16[16];
#pragma unroll
      for (int dd = 0; dd < 8; ++dd) {
        h2 uh = uhreg[o*8 + dd];
        v16[2*dd]     = co[o] * (float)uh.x;
        v16[2*dd + 1] = co[o] * (float)uh.y;
      }
      float v8[8];
#pragma unroll
      for (int i = 0; i < 8; ++i) {
        float keep = s0 ? v16[i+8] : v16[i];
        float send = s0 ? v16[i]   : v16[i+8];
        v8[i] = keep + __shfl_xor(send, 1);
      }
      float v4[4];
#pragma unroll
      for (int i = 0; i < 4; ++i) {
        float keep = s1 ? v8[i+4] : v8[i];
        float send = s1 ? v8[i]   : v8[i+4];
        v4[i] = keep + __shfl_xor(send, 2);
      }
      float v2[2];
#pragma unroll
      for (int i = 0; i < 2; ++i) {
        float keep = s2 ? v2[0]*0.f + v4[i+2] : v4[i];   // avoid compiler reorder quirk
        float send = s2 ? v4[i]   : v4[i+2];
        v2[i] = (s2 ? v4[i+2] : v4[i]) + __shfl_xor(send, 4);
      }
      float v1;
      {
        float keep = s3 ? v2[1] : v2[0];
        float send = s3 ? v2[0] : v2[1];
        v1 = keep + __shfl_xor(send, 8);
      }
      v1 += __shfl_xor(v1, 16);
      v1 += __shfl_xor(v1, 32);
      if (lane < 16) part[w][o*16 + jmap] = v1;
    }
    __syncthreads();

    // stage-2: t<80 combines the 6 wave partials, squashes, broadcasts v
    if (t < 80) {
      float s = part[0][t] + part[1][t] + part[2][t]
              + part[3][t] + part[4][t] + part[5][t];
      float sq = s * s;
      sq += __shfl_xor(sq, 1);
      sq += __shfl_xor(sq, 2);
      sq += __shfl_xor(sq, 4);
      sq += __shfl_xor(sq, 8);   // sum over the 16 d of this o
      float f = sq / ((1.f + sq) * (sqrtf(sq) + EPSQ));
      if (it == 2) out[(size_t)b*80 + t] = s * f;
      else         svh16[t] = bc_u16((_Float16)(s * f));
    }
    __syncthreads();

    if (it < 2) {
      // logits update: dv = <tu, v> via packed fdot2 from registers + svh16
#pragma unroll
      for (int o = 0; o < 5; ++o) {
        uint4 sa = *(const uint4*)&svh16[o*16];
        uint4 sb = *(const uint4*)&svh16[o*16 + 8];
        float dv = 0.f;
        dv = fdot2f(uhreg[o*8+0], bc_h2(sa.x), dv);
        dv = fdot2f(uhreg[o*8+1], bc_h2(sa.y), dv);
        dv = fdot2f(uhreg[o*8+2], bc_h2(sa.z), dv);
        dv = fdot2f(uhreg[o*8+3], bc_h2(sa.w), dv);
        dv = fdot2f(uhreg[o*8+4], bc_h2(sb.x), dv);
        dv = fdot2f(uhreg[o*8+5], bc_h2(sb.y), dv);
        dv = fdot2f(uhreg[o*8+6], bc_h2(sb.z), dv);
        dv = fdot2f(uhreg[o*8+7], bc_h2(sb.w), dv);
        lg[o] += dv;
      }
    }
  }
}

extern "C" void kernel_launch(void* const* d_in, const int* in_sizes, int n_in,
                              void* d_out, int out_size, void* d_ws, size_t ws_size,
                              hipStream_t stream) {
  const float* x  = (const float*)d_in[0];
  const float* w1 = (const float*)d_in[1];
  const float* b1 = (const float*)d_in[2];
  const float* pw = (const float*)d_in[3];
  const float* b2 = (const float*)d_in[4];
  const float* Wf = (const float*)d_in[5];
  float* out = (float*)d_out;
  char* ws = (char*)d_ws;

  _Float16* wc16  = (_Float16*)(ws);
  _Float16* pwB16 = (_Float16*)(ws + 147456);
  _Float16* Whs   = (_Float16*)(ws + 167936);
  ushort_t* u16   = (ushort_t*)(ws + 659456);

  k0_prep<<<960, 256, 0, stream>>>(w1, pw, Wf, wc16, pwB16, Whs);
  k12_mfma<<<1366, 256, 0, stream>>>(x, b1, b2, wc16, pwB16, u16);
  k3_route<<<4096, 384, 0, stream>>>(u16, Whs, out);
}